// Round 1
// 271.516 us; speedup vs baseline: 1.0085x; 1.0085x over previous
//
#include <hip/hip_runtime.h>

#define NT 64
#define B_ 32
#define C_ 32
#define H_ 160
#define W_ 160
#define TH 20
#define TW 20
#define NPIX (TH*TW)     // 400
#define NRED (B_*NPIX)   // 12800
#define EPS 1e-5f

#define HP 40            // hlds channel stride (bf16): pixel step = 20 dwords -> <=2-way on b128
#define WSL 33           // wlds per-tap slab stride in co rows (33*40*2B: breaks 0-mod-32 tap stride)

typedef __bf16 bf16x8 __attribute__((ext_vector_type(8)));
typedef float  f32x4  __attribute__((ext_vector_type(4)));

// ============ Kernel A: per-(b,c)-plane coalesced stats, 1 barrier =========
__global__ __launch_bounds__(320) void statsA_kernel(const float* __restrict__ x,
                                                     float* __restrict__ ppS,
                                                     float* __restrict__ ppS2) {
    int blk = blockIdx.x;          // b*32 + c
    int b = blk >> 5;
    int c = blk & 31;
    const float* plane = x + ((long)(b*C_ + c)) * H_ * W_;

    int tid   = threadIdx.x;
    int col4  = tid % 40;          // f4 column (0..39), constant per thread
    int rbase = tid / 40;          // 0..7

    __shared__ float sh [8 * 321];
    __shared__ float sh2[8 * 321];

    #pragma unroll
    for (int tr = 0; tr < 8; ++tr) {
        float s = 0.f, s2 = 0.f;
        #pragma unroll
        for (int k = 0; k < 3; ++k) {
            int r20 = rbase + 8*k;
            if (r20 < 20) {
                int row = tr*20 + r20;
                float4 v = *(const float4*)(plane + row*W_ + col4*4);
                s  += v.x + v.y + v.z + v.w;
                s2 += v.x*v.x + v.y*v.y + v.z*v.z + v.w*v.w;
            }
        }
        sh [tr*321 + tid] = s;
        sh2[tr*321 + tid] = s2;
    }
    __syncthreads();

    if (tid < 64) {
        int tr = tid >> 3, tc = tid & 7;
        float ps = 0.f, ps2 = 0.f;
        #pragma unroll
        for (int rb = 0; rb < 8; ++rb)
            #pragma unroll
            for (int c5 = 0; c5 < 5; ++c5) {
                int t = tr*321 + rb*40 + tc*5 + c5;
                ps += sh[t]; ps2 += sh2[t];
            }
        int tl = tr*8 + tc;
        atomicAdd(&ppS [tl*C_ + c], ps);
        atomicAdd(&ppS2[tl*C_ + c], ps2);
    }
}

// ============ Kernel B: fused norm+relu + 9-tap MFMA conv + bias + residual
// v2: b128 LDS staging writes, tap-outer MFMA loop (B-frags from LDS, not
// hoisted into 72 regs), direct global stores with fp32 residual (obuf and
// phase 3 removed), halo-only zeroing. 2 barriers, 62,656 B LDS.
__global__ __launch_bounds__(512, 4) void fused_kernel(
        const float* __restrict__ x,
        const float* __restrict__ gamma,
        const float* __restrict__ beta,
        const float* __restrict__ conv_w,
        const float* __restrict__ conv_b,
        const float* __restrict__ ppS,
        const float* __restrict__ ppS2,
        float* __restrict__ out) {
    int blk = blockIdx.x;
    int tl = blk >> 5;
    int b  = blk & 31;
    int ti = (tl >> 3) * TH;
    int tj = (tl & 7)  * TW;
    int tid = threadIdx.x;

    // LDS layout (62,656 B -> 2 blocks/CU):
    //   hlds: [484 pix][40 ch] bf16, zero halo ring; ch 32..39 never read
    //   wlds: [9 tap][33 co-slots][40] bf16 at +38,720 (only co 0..31 used)
    //   scale/shift: fp32[32] each at the tail
    __shared__ __align__(16) unsigned char smem[62656];
    __bf16* hlds   = (__bf16*)smem;
    __bf16* wlds   = (__bf16*)(smem + 38720);
    float*  scale  = (float*)(smem + 62400);
    float*  shiftv = (float*)(smem + 62528);

    // ---- phase 0: zero halo ring, finalize BN coeffs, stage weights ----
    if (tid < 420) {                       // 84 halo pixels x 5 uint4 (80 B each)
        int hp = tid / 5, q = tid - hp*5;
        int P;
        if      (hp < 22) P = hp;                    // row 0
        else if (hp < 44) P = 462 + (hp - 22);       // row 21
        else if (hp < 64) P = (hp - 43) * 22;        // col 0, rows 1..20
        else              P = (hp - 63) * 22 + 21;   // col 21, rows 1..20
        ((uint4*)smem)[P*5 + q] = uint4{0,0,0,0};
    }
    if (tid < C_) {
        int c = tid;
        float s   = ppS [tl*C_ + c];
        float s2  = ppS2[tl*C_ + c];
        float m   = s / (float)NRED;
        float var = s2 / (float)NRED - m*m;
        float rs  = rsqrtf(var + EPS);
        float g   = gamma[tl*C_ + c];
        scale[c]  = g * rs;
        shiftv[c] = beta[tl*C_ + c] - m * rs * g;
    }
    {
        const float* wsrc = conv_w + (long)tl * (C_*C_*9);
        for (int f = tid; f < C_*C_*9; f += 512) {
            int co  = f / 288;
            int rem = f - co*288;
            int cin = rem / 9;
            int tap = rem - cin*9;
            wlds[(tap*WSL + co)*HP + cin] = (__bf16)wsrc[f];
        }
    }
    __syncthreads();

    // ---- phase 1: normalize+relu, 1 pixel x 8 channels per item, b128 write
    for (int idx = tid; idx < 4*NPIX; idx += 512) {   // 1600 items
        int cg = idx / NPIX;            // channel group 0..3
        int p  = idx - cg*NPIX;         // pixel 0..399 (lane-consecutive)
        int y  = p / 20;
        int xx = p - y*20;
        int c0 = cg*8;
        const float* ps = x + (((long)(b*C_ + c0)*H_ + ti + y)*W_ + tj + xx);
        float v[8];
        #pragma unroll
        for (int k = 0; k < 8; ++k) v[k] = ps[k * (H_*W_)];
        bf16x8 h;
        #pragma unroll
        for (int k = 0; k < 8; ++k)
            h[k] = (__bf16)fmaxf(v[k]*scale[c0+k] + shiftv[c0+k], 0.f);
        *(bf16x8*)&hlds[((y+1)*22 + xx + 1)*HP + c0] = h;
    }
    __syncthreads();

    // ---- phase 2: tap-outer 9-tap GEMM, direct stores with fp32 residual
    int lane = tid & 63;
    int wv   = tid >> 6;            // wave 0..7
    int mm   = lane & 15;
    int jg   = lane >> 4;           // 0..3
    int j0   = jg * 8;
    float b0 = conv_b[tl*C_ + mm];
    float b1 = conv_b[tl*C_ + 16 + mm];

    auto store_chunk = [&](int chunk, f32x4 a0, f32x4 a1) {
        // D layout: col = lane&15 (co), row = jg*4 + r (pixel) -> 4 consecutive
        // pixels; runs of 4 never cross the 20-wide tile row.
        int pb = chunk*16 + jg*4;
        int py = pb / 20;
        int px = pb - py*20;
        long o0 = ((long)(b*C_ + mm)*H_ + ti + py)*W_ + tj + px;
        long o1 = o0 + (long)16*H_*W_;
        float4 x0 = *(const float4*)&x[o0];     // residual: L2-hot (same tile read in phase 1)
        float4 x1 = *(const float4*)&x[o1];
        float4 r0 = make_float4(a0[0]+x0.x, a0[1]+x0.y, a0[2]+x0.z, a0[3]+x0.w);
        float4 r1 = make_float4(a1[0]+x1.x, a1[1]+x1.y, a1[2]+x1.z, a1[3]+x1.w);
        *(float4*)&out[o0] = r0;
        *(float4*)&out[o1] = r1;
    };

    // 3 chunks per wave (chunk = wv + 8*i); wave 0 takes chunk 24 afterwards
    const __bf16* ab[3];
    #pragma unroll
    for (int i = 0; i < 3; ++i) {
        int p  = (wv + 8*i)*16 + mm;
        int py = p / 20;
        int px = p - py*20;
        ab[i] = &hlds[(py*22 + px)*HP + j0];
    }
    f32x4 acc[3][2];
    #pragma unroll
    for (int i = 0; i < 3; ++i) {
        acc[i][0] = f32x4{b0,b0,b0,b0};
        acc[i][1] = f32x4{b1,b1,b1,b1};
    }
    #pragma unroll
    for (int tap = 0; tap < 9; ++tap) {
        const int ky = tap/3, kx = tap - (tap/3)*3;
        bf16x8 w0 = *(const bf16x8*)&wlds[(tap*WSL + mm)*HP + j0];
        bf16x8 w1 = *(const bf16x8*)&wlds[(tap*WSL + 16 + mm)*HP + j0];
        #pragma unroll
        for (int i = 0; i < 3; ++i) {
            bf16x8 af = *(const bf16x8*)(ab[i] + (ky*22 + kx)*HP);  // imm offsets off one vaddr
            acc[i][0] = __builtin_amdgcn_mfma_f32_16x16x32_bf16(af, w0, acc[i][0], 0, 0, 0);
            acc[i][1] = __builtin_amdgcn_mfma_f32_16x16x32_bf16(af, w1, acc[i][1], 0, 0, 0);
        }
    }
    #pragma unroll
    for (int i = 0; i < 3; ++i) store_chunk(wv + 8*i, acc[i][0], acc[i][1]);

    if (wv == 0) {   // wave-uniform branch: the 25th chunk
        int p  = 24*16 + mm;
        int py = p / 20;
        int px = p - py*20;
        const __bf16* a3 = &hlds[(py*22 + px)*HP + j0];
        f32x4 c0v = f32x4{b0,b0,b0,b0};
        f32x4 c1v = f32x4{b1,b1,b1,b1};
        #pragma unroll
        for (int tap = 0; tap < 9; ++tap) {
            const int ky = tap/3, kx = tap - (tap/3)*3;
            bf16x8 w0 = *(const bf16x8*)&wlds[(tap*WSL + mm)*HP + j0];
            bf16x8 w1 = *(const bf16x8*)&wlds[(tap*WSL + 16 + mm)*HP + j0];
            bf16x8 af = *(const bf16x8*)(a3 + (ky*22 + kx)*HP);
            c0v = __builtin_amdgcn_mfma_f32_16x16x32_bf16(af, w0, c0v, 0, 0, 0);
            c1v = __builtin_amdgcn_mfma_f32_16x16x32_bf16(af, w1, c1v, 0, 0, 0);
        }
        store_chunk(24, c0v, c1v);
    }
}

extern "C" void kernel_launch(void* const* d_in, const int* in_sizes, int n_in,
                              void* d_out, int out_size, void* d_ws, size_t ws_size,
                              hipStream_t stream) {
    const float* x      = (const float*)d_in[0];
    const float* gamma  = (const float*)d_in[1];
    const float* beta   = (const float*)d_in[2];
    const float* conv_w = (const float*)d_in[3];
    const float* conv_b = (const float*)d_in[4];
    float* out = (float*)d_out;

    float* ppS  = (float*)d_ws;          // 2048 floats
    float* ppS2 = ppS + NT*C_;           // 2048 floats

    hipMemsetAsync(d_ws, 0, 2 * NT * C_ * sizeof(float), stream);
    statsA_kernel<<<B_ * C_, 320, 0, stream>>>(x, ppS, ppS2);
    fused_kernel<<<NT * B_, 512, 0, stream>>>(x, gamma, beta, conv_w, conv_b,
                                              ppS, ppS2, out);
}